// Round 13
// baseline (286.887 us; speedup 1.0000x reference)
//
#include <hip/hip_runtime.h>
#include <math.h>

#define D 256
#define K 1024
#define NR 65536
#define ST_SIZE (NR * D)          // 16777216
#define LOSS_OFF ST_SIZE
#define IDX_OFF (ST_SIZE + 1)
#define BM 128
#define TPB 256
#define HCG 16                    // cgs per K-half (512 codes)
#define MARGIN 2e-3f
#define CAND_CAP 2048

typedef short bf16x8 __attribute__((ext_vector_type(8)));
typedef float f32x16 __attribute__((ext_vector_type(16)));

// f32 -> bf16 RNE (bit-level)
__device__ __forceinline__ unsigned f2bf(float f) {
    unsigned u = __float_as_uint(f);
    return (u + 0x7FFFu + ((u >> 16) & 1u)) >> 16;
}
__device__ __forceinline__ uint4 packB(float4 a, float4 b) {
    uint4 w;
    w.x = f2bf(-2.f * a.x) | (f2bf(-2.f * a.y) << 16);
    w.y = f2bf(-2.f * a.z) | (f2bf(-2.f * a.w) << 16);
    w.z = f2bf(-2.f * b.x) | (f2bf(-2.f * b.y) << 16);
    w.w = f2bf(-2.f * b.z) | (f2bf(-2.f * b.w) << 16);
    return w;
}

// anti-contraction square (numpy-identical rounding: mul rounded alone)
__device__ __forceinline__ float sq_nf(float x) {
    float s = x * x;
    asm volatile("" : "+v"(s));
    return s;
}
// numpy pairwise sum of squares over 256 elements (bit-exact, validated r2-r12)
template <typename F>
__device__ __forceinline__ float np_sumsq256(F ld) {
    float tot[2];
    #pragma unroll
    for (int h = 0; h < 2; ++h) {
        const int base = h * 128;
        float r[8];
        #pragma unroll
        for (int j = 0; j < 8; ++j) r[j] = sq_nf(ld(base + j));
        for (int i = 8; i < 128; i += 8) {
            #pragma unroll
            for (int j = 0; j < 8; ++j) r[j] += sq_nf(ld(base + i + j));
        }
        tot[h] = ((r[0] + r[1]) + (r[2] + r[3])) + ((r[4] + r[5]) + (r[6] + r[7]));
    }
    return tot[0] + tot[1];
}

// prep: blocks 0..127 pack bf16(-2e) in MFMA fragment order; blocks 128..131 se
__global__ void prep_kernel(const float* __restrict__ emb,
                            unsigned short* __restrict__ pb,
                            float* __restrict__ se) {
    if (blockIdx.x < 128) {
        const int c  = blockIdx.x * 256 + threadIdx.x;    // chunk id, 32768 total
        const int cg = c >> 10, r = c & 1023;
        const int ks = r >> 6,  l = r & 63;
        const float4* s4 = (const float4*)(emb + (size_t)(cg * 32 + (l & 31)) * D
                                               + ks * 16 + (l >> 5) * 8);
        ((uint4*)pb)[c] = packB(s4[0], s4[1]);
    } else {
        const int k = (blockIdx.x - 128) * 256 + threadIdx.x;   // < 1024
        const float* row = emb + (size_t)k * D;
        se[k] = np_sumsq256([&](int i) { return row[i]; });
    }
}

// k1: K-split search. grid = 1024 (512 row-blocks x 2 K-halves), 4 blocks/CU.
// Winner merge via global u64 atomicMin on key = (d_bits<<10)|code (numpy order).
__global__ __launch_bounds__(TPB, 1)
void vq_search(const float* __restrict__ inp, const float* __restrict__ emb,
               const unsigned short* __restrict__ pb, const float* __restrict__ se,
               unsigned long long* __restrict__ keys) {
    __shared__ __align__(16) unsigned short Bt[8192];      // 16 KB single buffer
    __shared__ float se_s[512];                            //  2 KB (own half)
    __shared__ float sx_s[BM];                             // .5 KB
    __shared__ float rfin[BM];                             // .5 KB
    __shared__ unsigned cand[CAND_CAP];                    //  8 KB
    __shared__ float candsc[CAND_CAP];                     //  8 KB  (~35 KB tot)
    __shared__ int ncand;

    const int t   = threadIdx.x;
    const int ws  = t >> 6;      // wave 0..3 (rows ws*32 .. ws*32+31)
    const int l   = t & 63;
    const int col = l & 31;
    const int hi  = l >> 5;
    const int rb  = blockIdx.x >> 1;
    const int kh  = blockIdx.x & 1;      // K-half: codes kh*512 .. kh*512+511
    const int r0  = rb * BM;

    #pragma unroll
    for (int i = 0; i < 2; ++i) se_s[i * TPB + t] = se[kh * 512 + i * TPB + t];
    if (t == 0) ncand = 0;

    // ---- A fragments: rows r0 + ws*32 + col, k = ks*16 + hi*8 + j ----
    bf16x8 afr[16];
    {
        const float* xrow = inp + (size_t)(r0 + ws * 32 + col) * D;
        #pragma unroll
        for (int ks = 0; ks < 16; ++ks) {
            const float4* p4 = (const float4*)(xrow + ks * 16 + hi * 8);
            float4 a = p4[0], b = p4[1];
            bf16x8 v;
            v[0] = (short)f2bf(a.x); v[1] = (short)f2bf(a.y);
            v[2] = (short)f2bf(a.z); v[3] = (short)f2bf(a.w);
            v[4] = (short)f2bf(b.x); v[5] = (short)f2bf(b.y);
            v[6] = (short)f2bf(b.z); v[7] = (short)f2bf(b.w);
            afr[ks] = v;
        }
    }

    // ---- fused sx: numpy-pairwise-exact, 16 lanes per row (pure shfl) ----
    {
        const int slot = t & 15, grp = t >> 4;   // 16 groups of 16 lanes
        const int j = slot & 7, h = slot >> 3;
        for (int p = 0; p < 8; ++p) {
            const int row = p * 16 + grp;
            const float* base = inp + (size_t)(r0 + row) * D + h * 128 + j;
            float s = sq_nf(base[0]);
            #pragma unroll
            for (int i = 1; i < 16; ++i) s += sq_nf(base[i * 8]);
            #pragma unroll
            for (int m = 1; m <= 8; m <<= 1) s += __shfl_xor(s, m);  // local-left
            if (slot == 0) sx_s[row] = s;
        }
    }

    float rmin[16];
    #pragma unroll
    for (int i = 0; i < 16; ++i) rmin[i] = INFINITY;

    const uint4* src = (const uint4*)pb + (size_t)kh * HCG * 1024;  // half base

    // ---- prologue: stage cg 0 ----
    {
        uint4* bt = (uint4*)Bt;
        #pragma unroll
        for (int q = 0; q < 4; ++q) bt[q * TPB + t] = src[q * TPB + t];
    }
    // ---- single sweep over this half's 16 cgs (single-buffer, reg prefetch) ----
    for (int lc = 0; lc < HCG; ++lc) {
        __syncthreads();                       // tile published (+inits on lc=0)
        uint4 pf[4];
        const bool haspf = (lc + 1 < HCG);
        if (haspf) {                           // issue next-tile loads early
            #pragma unroll
            for (int q = 0; q < 4; ++q)
                pf[q] = src[(size_t)(lc + 1) * 1024 + q * TPB + t];
        }
        const int cg = kh * HCG + lc;          // global cg
        const float sev = se_s[lc * 32 + col];
        f32x16 aE, aO;
        #pragma unroll
        for (int i = 0; i < 16; ++i) { aE[i] = sev; aO[i] = 0.f; }
        const bf16x8* bp = (const bf16x8*)Bt;
        #pragma unroll
        for (int ks = 0; ks < 16; ks += 2) {
            aE = __builtin_amdgcn_mfma_f32_32x32x16_bf16(afr[ks],     bp[ks * 64 + l],       aE, 0, 0, 0);
            aO = __builtin_amdgcn_mfma_f32_32x32x16_bf16(afr[ks + 1], bp[(ks + 1) * 64 + l], aO, 0, 0, 0);
        }
        float sc[16];
        #pragma unroll
        for (int i = 0; i < 16; ++i) sc[i] = aE[i] + aO[i];

        // running row-min: lane-local always; butterfly on even lcs
        // (staleness only raises the threshold => superset => safe)
        #pragma unroll
        for (int i = 0; i < 16; ++i) rmin[i] = fminf(rmin[i], sc[i]);
        if ((lc & 1) == 0) {
            #pragma unroll
            for (int i = 0; i < 16; ++i) {
                #pragma unroll
                for (int m = 1; m < 32; m <<= 1)
                    rmin[i] = fminf(rmin[i], __shfl_xor(rmin[i], m));
            }
        }
        #pragma unroll
        for (int i = 0; i < 16; ++i) {
            if (sc[i] <= rmin[i] + MARGIN) {
                const int row_local = ws * 32 + (i & 3) + 8 * (i >> 2) + 4 * hi;
                const int p = atomicAdd(&ncand, 1);
                if (p < CAND_CAP) {
                    cand[p]   = ((unsigned)row_local << 10) | (unsigned)(cg * 32 + col);
                    candsc[p] = sc[i];
                }
            }
        }
        __syncthreads();                       // all waves done reading Bt
        if (haspf) {
            uint4* bt = (uint4*)Bt;
            #pragma unroll
            for (int q = 0; q < 4; ++q) bt[q * TPB + t] = pf[q];
        }
    }
    // final butterfly -> exact per-row (own-half) approx-min for the filter
    #pragma unroll
    for (int i = 0; i < 16; ++i) {
        #pragma unroll
        for (int m = 1; m < 32; m <<= 1)
            rmin[i] = fminf(rmin[i], __shfl_xor(rmin[i], m));
    }
    if (col == 0) {
        #pragma unroll
        for (int i = 0; i < 16; ++i)
            rfin[ws * 32 + (i & 3) + 8 * (i >> 2) + 4 * hi] = rmin[i];
    }
    __syncthreads();                               // cand list + rfin complete

    // ---- filter + exact f32 rescore -> global u64 key atomicMin ----
    int n = ncand; if (n > CAND_CAP) n = CAND_CAP;
    {
        const int qw = l >> 4, lq = l & 15;        // quarter-wave, lane-in-quarter
        for (int ci = ws * 4 + qw; ci < n; ci += 16) {
            const unsigned uc = cand[ci];
            const int row_local = uc >> 10, code = uc & 1023;
            if (candsc[ci] <= rfin[row_local] + MARGIN) {  // own-half winner kept
                const float4* xp = (const float4*)(inp + (size_t)(r0 + row_local) * D) + lq * 4;
                const float4* ep = (const float4*)(emb + (size_t)code * D) + lq * 4;
                float p = 0.f;
                #pragma unroll
                for (int q = 0; q < 4; ++q) {
                    float4 x = xp[q], e = ep[q];
                    p = fmaf(x.x, e.x, p);
                    p = fmaf(x.y, e.y, p);
                    p = fmaf(x.z, e.z, p);
                    p = fmaf(x.w, e.w, p);
                }
                #pragma unroll
                for (int m = 1; m <= 8; m <<= 1) p += __shfl_xor(p, m);
                const float tv = sx_s[row_local] + se_s[code - kh * 512];
                const float d  = fmaf(-2.f, p, tv);    // = fl(t - 2*dot), matches numpy
                if (lq == 0) {                          // d>0 => key order = numpy order
                    const unsigned long long key =
                        ((unsigned long long)__float_as_uint(d) << 10) | (unsigned)code;
                    atomicMin(&keys[r0 + row_local], key);
                }
            }
        }
    }
}

// k2: streaming epilogue — st(=q) + idx + loss from keys
__global__ __launch_bounds__(256, 8)
void vq_epi(const float* __restrict__ emb, const unsigned long long* __restrict__ keys,
            float* __restrict__ out, double* __restrict__ loss_acc) {
    __shared__ double lred[256];
    const int t = threadIdx.x;
    const int gsz = gridDim.x * 256;
    float4*       out4 = (float4*)out;
    const float4* emb4 = (const float4*)emb;

    double lp = 0.0;
    for (int e = blockIdx.x * 256 + t; e < ST_SIZE / 4; e += gsz) {
        const int row = e >> 6, c4 = e & 63;
        const unsigned long long key = keys[row];
        const int code = (int)(key & 1023u);
        out4[e] = emb4[((size_t)code << 6) + c4];      // st = q (r12-validated)
        if (c4 == 0) {
            out[IDX_OFF + row] = (float)code;
            lp += (double)__uint_as_float((unsigned)(key >> 10));  // winner d
        }
    }
    lred[t] = lp;
    __syncthreads();
    #pragma unroll
    for (int s = 128; s; s >>= 1) {
        if (t < s) lred[t] += lred[t + s];
        __syncthreads();
    }
    if (t == 0) atomicAdd(loss_acc, lred[0]);
}

__global__ void fin_kernel(const double* __restrict__ loss_acc, float* __restrict__ out) {
    out[LOSS_OFF] = (float)(1.25 * loss_acc[0] / (double)ST_SIZE);
}

extern "C" void kernel_launch(void* const* d_in, const int* in_sizes, int n_in,
                              void* d_out, int out_size, void* d_ws, size_t ws_size,
                              hipStream_t stream) {
    const float* inp = (const float*)d_in[0];
    const float* emb = (const float*)d_in[1];
    float* out = (float*)d_out;
    unsigned short* pb   = (unsigned short*)d_ws;                       // 512 KB
    float*  se_ws        = (float*)((char*)d_ws + 524288);              //   4 KB
    unsigned long long* keys = (unsigned long long*)((char*)d_ws + 528384); // 512 KB
    double* loss_acc     = (double*)((char*)d_ws + 1052672);            //   8 B

    hipMemsetAsync(keys, 0xFF, NR * sizeof(unsigned long long), stream);
    hipMemsetAsync(loss_acc, 0, sizeof(double), stream);
    prep_kernel<<<132, 256, 0, stream>>>(emb, pb, se_ws);
    vq_search<<<2 * NR / BM, TPB, 0, stream>>>(inp, emb, pb, se_ws, keys);
    vq_epi<<<2048, 256, 0, stream>>>(emb, keys, out, loss_acc);
    fin_kernel<<<1, 1, 0, stream>>>(loss_acc, out);
}

// Round 14
// 184.760 us; speedup vs baseline: 1.5528x; 1.5528x over previous
//
#include <hip/hip_runtime.h>
#include <math.h>

#define D 256
#define K 1024
#define NR 65536
#define ST_SIZE (NR * D)          // 16777216
#define LOSS_OFF ST_SIZE
#define IDX_OFF (ST_SIZE + 1)
#define BM 128
#define TPB 256
#define NCG 32
#define NBLK (NR / BM)            // 512
#define MARGIN 2e-3f
#define CAND_CAP 3072

typedef short bf16x8 __attribute__((ext_vector_type(8)));
typedef float f32x16 __attribute__((ext_vector_type(16)));

// f32 -> bf16 RNE (bit-level)
__device__ __forceinline__ unsigned f2bf(float f) {
    unsigned u = __float_as_uint(f);
    return (u + 0x7FFFu + ((u >> 16) & 1u)) >> 16;
}
__device__ __forceinline__ uint4 packB(float4 a, float4 b) {
    uint4 w;
    w.x = f2bf(-2.f * a.x) | (f2bf(-2.f * a.y) << 16);
    w.y = f2bf(-2.f * a.z) | (f2bf(-2.f * a.w) << 16);
    w.z = f2bf(-2.f * b.x) | (f2bf(-2.f * b.y) << 16);
    w.w = f2bf(-2.f * b.z) | (f2bf(-2.f * b.w) << 16);
    return w;
}

// anti-contraction square (numpy-identical rounding: mul rounded alone)
__device__ __forceinline__ float sq_nf(float x) {
    float s = x * x;
    asm volatile("" : "+v"(s));
    return s;
}
// numpy pairwise sum of squares over 256 elements (bit-exact, validated r2-r13)
template <typename F>
__device__ __forceinline__ float np_sumsq256(F ld) {
    float tot[2];
    #pragma unroll
    for (int h = 0; h < 2; ++h) {
        const int base = h * 128;
        float r[8];
        #pragma unroll
        for (int j = 0; j < 8; ++j) r[j] = sq_nf(ld(base + j));
        for (int i = 8; i < 128; i += 8) {
            #pragma unroll
            for (int j = 0; j < 8; ++j) r[j] += sq_nf(ld(base + i + j));
        }
        tot[h] = ((r[0] + r[1]) + (r[2] + r[3])) + ((r[4] + r[5]) + (r[6] + r[7]));
    }
    return tot[0] + tot[1];
}

// prep: blocks 0..127 pack bf16(-2e) in MFMA fragment order; blocks 128..131 se
__global__ void prep_kernel(const float* __restrict__ emb,
                            unsigned short* __restrict__ pb,
                            float* __restrict__ se) {
    if (blockIdx.x < 128) {
        const int c  = blockIdx.x * 256 + threadIdx.x;    // chunk id, 32768 total
        const int cg = c >> 10, r = c & 1023;
        const int ks = r >> 6,  l = r & 63;
        const float4* s4 = (const float4*)(emb + (size_t)(cg * 32 + (l & 31)) * D
                                               + ks * 16 + (l >> 5) * 8);
        ((uint4*)pb)[c] = packB(s4[0], s4[1]);
    } else {
        const int k = (blockIdx.x - 128) * 256 + threadIdx.x;   // < 1024
        const float* row = emb + (size_t)k * D;
        se[k] = np_sumsq256([&](int i) { return row[i]; });
    }
}

// main: LDS-staged inp (coalesced stream) -> A-frags + sx from LDS;
//       single-sweep MFMA prune + filtered exact rescore + st(=q) + loss(=bestd)
__global__ __launch_bounds__(TPB, 3)
void vq_main(const float* __restrict__ inp, const float* __restrict__ emb,
             const unsigned short* __restrict__ pb, const float* __restrict__ se,
             float* __restrict__ out, double* __restrict__ lsum) {
    // aliased pool: phase A = xs[32][260] f32 staging quarter (33.3 KB);
    //              phase B = Bt 16 KB | cand 12 KB | candsc 12 KB (40 KB)
    __shared__ __align__(16) char pool[40960];
    __shared__ float se_s[K];                              //  4 KB
    __shared__ float sx_s[BM];                             // .5 KB
    __shared__ float rfin[BM];                             // .5 KB
    __shared__ unsigned bestd[BM];                         // .5 KB
    __shared__ unsigned bestc[BM];                         // .5 KB (~46.2 KB tot)
    __shared__ int ncand;

    float (*xs)[260]       = (float (*)[260])pool;
    unsigned short* Bt     = (unsigned short*)pool;
    unsigned* cand         = (unsigned*)(pool + 16384);
    float*    candsc       = (float*)(pool + 16384 + 12288);

    const int t   = threadIdx.x;
    const int ws  = t >> 6;      // wave 0..3 (rows ws*32 .. ws*32+31)
    const int l   = t & 63;
    const int col = l & 31;
    const int hi  = l >> 5;
    const int r0  = blockIdx.x * BM;

    #pragma unroll
    for (int i = 0; i < K / TPB; ++i) se_s[i * TPB + t] = se[i * TPB + t];
    if (t < BM) { bestd[t] = 0xFFFFFFFFu; bestc[t] = 0xFFFFFFFFu; }
    if (t == 0) ncand = 0;

    // ---- phase A: 4 quarters of 32 rows: coalesced stage -> extract + sx ----
    bf16x8 afr[16];
    {
        const int slot = t & 15, grp = t >> 4;   // sx: 16 groups of 16 lanes
        const int j = slot & 7, h = slot >> 3;
        for (int q = 0; q < 4; ++q) {
            __syncthreads();                     // xs free (prev extract/sx done)
            const float4* inq = (const float4*)(inp + (size_t)(r0 + q * 32) * D);
            #pragma unroll
            for (int i = 0; i < 8; ++i) {        // 2048 float4, coalesced
                const int e = i * TPB + t;
                *(float4*)&xs[e >> 6][(e & 63) * 4] = inq[e];
            }
            __syncthreads();                     // quarter staged
            if (ws == q) {                       // A-frags for rows q*32+col
                #pragma unroll
                for (int ks = 0; ks < 16; ++ks) {
                    float4 a = *(const float4*)&xs[col][ks * 16 + hi * 8];
                    float4 b = *(const float4*)&xs[col][ks * 16 + hi * 8 + 4];
                    bf16x8 v;
                    v[0] = (short)f2bf(a.x); v[1] = (short)f2bf(a.y);
                    v[2] = (short)f2bf(a.z); v[3] = (short)f2bf(a.w);
                    v[4] = (short)f2bf(b.x); v[5] = (short)f2bf(b.y);
                    v[6] = (short)f2bf(b.z); v[7] = (short)f2bf(b.w);
                    afr[ks] = v;
                }
            }
            // sx: numpy-pairwise-exact (identical arithmetic to r12, LDS source)
            for (int p = 0; p < 2; ++p) {
                const int rloc = p * 16 + grp;
                const float* base = &xs[rloc][h * 128 + j];
                float s = sq_nf(base[0]);
                #pragma unroll
                for (int i = 1; i < 16; ++i) s += sq_nf(base[i * 8]);
                #pragma unroll
                for (int m = 1; m <= 8; m <<= 1) s += __shfl_xor(s, m);  // local-left
                if (slot == 0) sx_s[q * 32 + rloc] = s;
            }
        }
    }
    __syncthreads();                             // xs dead; pool -> phase B

    float rmin[16];
    #pragma unroll
    for (int i = 0; i < 16; ++i) rmin[i] = INFINITY;

    const uint4* src = (const uint4*)pb;

    // ---- single sweep: single-buffer Bt + reg prefetch (r13-proven cadence) ----
    {
        uint4* bt = (uint4*)Bt;
        #pragma unroll
        for (int q = 0; q < 4; ++q) bt[q * TPB + t] = src[q * TPB + t];
    }
    for (int cg = 0; cg < NCG; ++cg) {
        __syncthreads();                       // tile published
        uint4 pf[4];
        const bool haspf = (cg + 1 < NCG);
        if (haspf) {                           // issue next-tile loads early
            #pragma unroll
            for (int q = 0; q < 4; ++q)
                pf[q] = src[(size_t)(cg + 1) * 1024 + q * TPB + t];
        }
        // score = se - 2*x.e via MFMA, C-init = se[col]; two indep acc chains
        const float sev = se_s[cg * 32 + col];
        f32x16 aE, aO;
        #pragma unroll
        for (int i = 0; i < 16; ++i) { aE[i] = sev; aO[i] = 0.f; }
        const bf16x8* bp = (const bf16x8*)Bt;
        #pragma unroll
        for (int ks = 0; ks < 16; ks += 2) {
            aE = __builtin_amdgcn_mfma_f32_32x32x16_bf16(afr[ks],     bp[ks * 64 + l],       aE, 0, 0, 0);
            aO = __builtin_amdgcn_mfma_f32_32x32x16_bf16(afr[ks + 1], bp[(ks + 1) * 64 + l], aO, 0, 0, 0);
        }
        float sc[16];
        #pragma unroll
        for (int i = 0; i < 16; ++i) sc[i] = aE[i] + aO[i];

        // running row-min: lane-local always; butterfly on even cgs
        // (staleness only raises the threshold => superset => safe)
        #pragma unroll
        for (int i = 0; i < 16; ++i) rmin[i] = fminf(rmin[i], sc[i]);
        if ((cg & 1) == 0) {
            #pragma unroll
            for (int i = 0; i < 16; ++i) {
                #pragma unroll
                for (int m = 1; m < 32; m <<= 1)
                    rmin[i] = fminf(rmin[i], __shfl_xor(rmin[i], m));
            }
        }
        #pragma unroll
        for (int i = 0; i < 16; ++i) {
            if (sc[i] <= rmin[i] + MARGIN) {
                const int row_local = ws * 32 + (i & 3) + 8 * (i >> 2) + 4 * hi;
                const int p = atomicAdd(&ncand, 1);
                if (p < CAND_CAP) {
                    cand[p]   = ((unsigned)row_local << 10) | (unsigned)(cg * 32 + col);
                    candsc[p] = sc[i];
                }
            }
        }
        __syncthreads();                       // all waves done reading Bt
        if (haspf) {
            uint4* bt = (uint4*)Bt;
            #pragma unroll
            for (int q = 0; q < 4; ++q) bt[q * TPB + t] = pf[q];
        }
    }
    // final butterfly -> exact per-row approx-min; publish for the filter
    #pragma unroll
    for (int i = 0; i < 16; ++i) {
        #pragma unroll
        for (int m = 1; m < 32; m <<= 1)
            rmin[i] = fminf(rmin[i], __shfl_xor(rmin[i], m));
    }
    if (col == 0) {
        #pragma unroll
        for (int i = 0; i < 16; ++i)
            rfin[ws * 32 + (i & 3) + 8 * (i >> 2) + 4 * hi] = rmin[i];
    }
    __syncthreads();                               // cand list + rfin complete

    // ---- filter + exact f32 rescore: 16 lanes per candidate (L2-warm x) ----
    int n = ncand; if (n > CAND_CAP) n = CAND_CAP;
    {
        const int qw = l >> 4, lq = l & 15;        // quarter-wave, lane-in-quarter
        for (int ci = ws * 4 + qw; ci < n; ci += 16) {
            const unsigned uc = cand[ci];
            const int row_local = uc >> 10, code = uc & 1023;
            const float sc = candsc[ci];
            if (sc <= rfin[row_local] + MARGIN) {  // survives final-min filter
                const float4* xp = (const float4*)(inp + (size_t)(r0 + row_local) * D) + lq * 4;
                const float4* ep = (const float4*)(emb + (size_t)code * D) + lq * 4;
                float p = 0.f;
                #pragma unroll
                for (int q = 0; q < 4; ++q) {
                    float4 x = xp[q], e = ep[q];
                    p = fmaf(x.x, e.x, p);
                    p = fmaf(x.y, e.y, p);
                    p = fmaf(x.z, e.z, p);
                    p = fmaf(x.w, e.w, p);
                }
                #pragma unroll
                for (int m = 1; m <= 8; m <<= 1) p += __shfl_xor(p, m);
                const float tv = sx_s[row_local] + se_s[code];
                const float d  = fmaf(-2.f, p, tv);    // = fl(t - 2*dot), matches numpy
                if (lq == 0) {
                    candsc[ci] = d;
                    atomicMin(&bestd[row_local], __float_as_uint(d));  // d>0: uint-monotone
                }
            } else if (lq == 0) {
                candsc[ci] = INFINITY;             // can't match bestd in phase 2
            }
        }
    }
    __syncthreads();
    for (int ci = t; ci < n; ci += TPB) {          // tie-break: lowest code at min d
        const unsigned uc = cand[ci];
        if (__float_as_uint(candsc[ci]) == bestd[uc >> 10])
            atomicMin(&bestc[uc >> 10], uc & 1023u);
    }
    __syncthreads();
    if (t < BM) out[IDX_OFF + r0 + t] = (float)bestc[t];

    // ---- st = q (r12-validated, |err| <= 6e-7 << thr): pure q-write ----
    {
        float4* out4 = (float4*)(out + (size_t)r0 * D);
        const float4* emb4 = (const float4*)emb;
        #pragma unroll
        for (int i = 0; i < (BM * D) / (4 * TPB); ++i) {   // 32 iters
            const int e = i * TPB + t;
            const int row = e >> 6, c4 = e & 63;
            out4[e] = emb4[((size_t)bestc[row] << 6) + c4];
        }
    }

    // ---- loss partial: sum of winner distances (bestd) in f64, fixed tree ----
    if (t < 64) {
        double s = (double)__uint_as_float(bestd[t]) + (double)__uint_as_float(bestd[t + 64]);
        #pragma unroll
        for (int m = 1; m < 64; m <<= 1) s += __shfl_xor(s, m);
        if (t == 0) lsum[blockIdx.x] = s;
    }
}

// fin: loss = 1.25 * sum(d_winner) / (N*D); one wave, fixed-tree reduction
__global__ void fin_kernel(const double* __restrict__ lsum, float* __restrict__ out) {
    const int l = threadIdx.x;                     // 64 lanes
    double s = 0.0;
    #pragma unroll
    for (int i = 0; i < NBLK / 64; ++i) s += lsum[l * (NBLK / 64) + i];
    #pragma unroll
    for (int m = 1; m < 64; m <<= 1) s += __shfl_xor(s, m);
    if (l == 0) out[LOSS_OFF] = (float)(1.25 * s / (double)ST_SIZE);
}

extern "C" void kernel_launch(void* const* d_in, const int* in_sizes, int n_in,
                              void* d_out, int out_size, void* d_ws, size_t ws_size,
                              hipStream_t stream) {
    const float* inp = (const float*)d_in[0];
    const float* emb = (const float*)d_in[1];
    float* out = (float*)d_out;
    unsigned short* pb = (unsigned short*)d_ws;               // 512 KB (frag-ordered bf16)
    float*  se_ws      = (float*)((char*)d_ws + 524288);      //   4 KB
    double* lsum       = (double*)((char*)d_ws + 528384);     //   4 KB (512 doubles)

    prep_kernel<<<132, 256, 0, stream>>>(emb, pb, se_ws);
    vq_main<<<NBLK, TPB, 0, stream>>>(inp, emb, pb, se_ws, out, lsum);
    fin_kernel<<<1, 64, 0, stream>>>(lsum, out);
}